// Round 1
// baseline (126.079 us; speedup 1.0000x reference)
//
#include <hip/hip_runtime.h>
#include <hip/hip_bf16.h>

typedef _Float16 half8 __attribute__((ext_vector_type(8)));
typedef _Float16 half4 __attribute__((ext_vector_type(4)));
typedef float floatx4 __attribute__((ext_vector_type(4)));

#define IN_DIM 256
#define OUT_DIM 256
#define M_TILE 64
#define ROWSTR 264  // 256 + 8 f16 pad: 528B row stride -> 2-way (free) LDS conflict on ds_read_b128

// Kernel 1: quantize weight -> f16 (exact: |w_q| <~ 500 < 2048), bias -> f32,
// and emit the tuple's scalar second output (s*scale).
__global__ void quant_kernel(const float* __restrict__ w,
                             const float* __restrict__ bias,
                             const float* __restrict__ in_scale,
                             _Float16* __restrict__ wq,
                             float* __restrict__ bq,
                             float* __restrict__ out_scalar) {
    int i = blockIdx.x * blockDim.x + threadIdx.x;
    if (i < OUT_DIM * IN_DIM) {
        // jnp.round == round-half-even -> rintf (v_rndne_f32), NOT roundf
        wq[i] = (_Float16)rintf(w[i] * 100.0f);
    }
    if (i < OUT_DIM) {
        float s2 = in_scale[0] * 100.0f;     // s * scale, fp32 like reference
        bq[i] = rintf(bias[i] * s2);
    }
    if (i == 0 && out_scalar != nullptr) {
        out_scalar[0] = in_scale[0] * 100.0f;
    }
}

// Kernel 2: out[64 rows x 256 cols] per block. 4 waves split N (64 cols each).
// c tile staged int32->f16 via LDS once; W fragments straight from global (L2-hot).
__global__ __launch_bounds__(256, 4) void gemm_kernel(const int* __restrict__ cx,
                                                      const _Float16* __restrict__ wq,
                                                      const float* __restrict__ bq,
                                                      float* __restrict__ out) {
    __shared__ _Float16 aT[M_TILE * ROWSTR];

    const int t = threadIdx.x;
    const size_t m0 = (size_t)blockIdx.x * M_TILE;

    // ---- stage: 64 rows x 256 int32, perfectly coalesced int4 loads ----
    // iter i: block reads contiguous 4KB chunk; thread t -> ints [i*1024 + t*4 .. +3]
    const int* cbase = cx + m0 * IN_DIM;
#pragma unroll
    for (int i = 0; i < 16; ++i) {
        int flat = i * 1024 + t * 4;
        int4 v = *(const int4*)(cbase + flat);
        int row = flat >> 8;       // /256
        int col = flat & 255;
        half4 h;
        h.x = (_Float16)v.x; h.y = (_Float16)v.y;
        h.z = (_Float16)v.z; h.w = (_Float16)v.w;
        *(half4*)&aT[row * ROWSTR + col] = h;   // 8B aligned: 264*2=528 %8==0, col%4==0
    }
    __syncthreads();

    const int wave = t >> 6;
    const int lane = t & 63;
    const int m16  = lane & 15;    // row within 16x16 A tile / col within B,C tiles
    const int quad = lane >> 4;    // k-group for A/B frags; row-group for C/D
    const int n0   = wave * 64;

    floatx4 acc[4][4] = {};        // 4 m_tiles x 4 n_tiles, 64 VGPRs

#pragma unroll
    for (int ks = 0; ks < 8; ++ks) {           // K = 256 in steps of 32
        const int kb = ks * 32 + quad * 8;
        half8 afr[4], bfr[4];
#pragma unroll
        for (int i = 0; i < 4; ++i)
            afr[i] = *(const half8*)&aT[(i * 16 + m16) * ROWSTR + kb];   // ds_read_b128
#pragma unroll
        for (int j = 0; j < 4; ++j)
            bfr[j] = *(const half8*)(wq + (size_t)(n0 + j * 16 + m16) * IN_DIM + kb);
#pragma unroll
        for (int i = 0; i < 4; ++i)
#pragma unroll
            for (int j = 0; j < 4; ++j)
                acc[i][j] = __builtin_amdgcn_mfma_f32_16x16x32_f16(afr[i], bfr[j], acc[i][j], 0, 0, 0);
    }

    // ---- epilogue: C/D layout col=lane&15, row=quad*4+reg ----
#pragma unroll
    for (int j = 0; j < 4; ++j) {
        int col = n0 + j * 16 + m16;
        float bv = bq[col];
#pragma unroll
        for (int i = 0; i < 4; ++i) {
#pragma unroll
            for (int r = 0; r < 4; ++r) {
                size_t row = m0 + i * 16 + quad * 4 + r;
                out[row * OUT_DIM + col] = acc[i][j][r] + bv;
            }
        }
    }
}

extern "C" void kernel_launch(void* const* d_in, const int* in_sizes, int n_in,
                              void* d_out, int out_size, void* d_ws, size_t ws_size,
                              hipStream_t stream) {
    const int*   cx       = (const int*)d_in[0];    // c_x int64 -> int32 per harness
    const float* w        = (const float*)d_in[1];
    const float* bias     = (const float*)d_in[2];
    const float* in_scale = (const float*)d_in[3];
    float* out = (float*)d_out;

    _Float16* wq = (_Float16*)d_ws;                              // 128 KB
    float*    bq = (float*)((char*)d_ws + OUT_DIM * IN_DIM * 2); // 1 KB

    const int rows = in_sizes[0] / IN_DIM;          // 65536
    const size_t gemm_elems = (size_t)rows * OUT_DIM;
    float* out_scalar = ((size_t)out_size > gemm_elems) ? (out + gemm_elems) : nullptr;

    quant_kernel<<<(OUT_DIM * IN_DIM + 255) / 256, 256, 0, stream>>>(
        w, bias, in_scale, wq, bq, out_scalar);

    gemm_kernel<<<rows / M_TILE, 256, 0, stream>>>(cx, wq, bq, out);
}

// Round 2
// 123.899 us; speedup vs baseline: 1.0176x; 1.0176x over previous
//
#include <hip/hip_runtime.h>

typedef _Float16 half8 __attribute__((ext_vector_type(8)));
typedef _Float16 half4 __attribute__((ext_vector_type(4)));
typedef float floatx4 __attribute__((ext_vector_type(4)));

#define IN_DIM 256
#define OUT_DIM 256
#define M_TILE 64
#define ROWSTR 264  // 256 + 8 f16 pad

// Quantize weight -> f16 in MFMA-A-fragment-permuted order:
//   perm[((ct*8 + ks)*64 + lane)*8 + e] = rne(W[ct*16 + (lane&15)][ks*32 + (lane>>4)*8 + e] * 100)
// so the gemm's A-frag load for (col-tile ct, k-step ks) is one fully-coalesced
// 16B/lane global_load_dwordx4. Also quantizes bias and writes the scalar output.
__global__ void quant_kernel(const float* __restrict__ w,
                             const float* __restrict__ bias,
                             const float* __restrict__ in_scale,
                             _Float16* __restrict__ wqp,
                             float* __restrict__ bq,
                             float* __restrict__ out_scalar) {
    int t = blockIdx.x * blockDim.x + threadIdx.x;   // 8192 threads, 8 elems each
    if (t < (OUT_DIM * IN_DIM) / 8) {
        int lane = t & 63;
        int ks   = (t >> 6) & 7;
        int ct   = t >> 9;
        int row  = ct * 16 + (lane & 15);
        int k0   = ks * 32 + (lane >> 4) * 8;
        const float* src = w + row * IN_DIM + k0;    // 32B contiguous per thread
        half8 h;
#pragma unroll
        for (int e = 0; e < 8; ++e)
            h[e] = (_Float16)rintf(src[e] * 100.0f); // jnp.round = round-half-even
        *((half8*)wqp + t) = h;
    }
    if (t < OUT_DIM) {
        float s2 = in_scale[0] * 100.0f;
        bq[t] = rintf(bias[t] * s2);
    }
    if (t == 0 && out_scalar != nullptr)
        out_scalar[0] = in_scale[0] * 100.0f;
}

// Per block: 64 batch rows x 256 out cols. A = W (permuted, coalesced global),
// B = c_x (staged int32->f16 via LDS). D: row(quad*4+reg)=out col, col(lane&15)=batch row
// -> float4 stores of 4 consecutive out cols per lane.
__global__ __launch_bounds__(256, 4) void gemm_kernel(const int* __restrict__ cx,
                                                      const _Float16* __restrict__ wqp,
                                                      const float* __restrict__ bq,
                                                      float* __restrict__ out) {
    __shared__ _Float16 cT[M_TILE * ROWSTR];

    const int t = threadIdx.x;
    const size_t m0 = (size_t)blockIdx.x * M_TILE;

    // ---- stage 64 rows x 256 int32 -> f16, coalesced int4 loads ----
    const int* cbase = cx + m0 * IN_DIM;
#pragma unroll
    for (int i = 0; i < 16; ++i) {
        int flat = i * 1024 + t * 4;
        int4 v = *(const int4*)(cbase + flat);
        int row = flat >> 8;
        int col = flat & 255;
        half4 h;
        h.x = (_Float16)v.x; h.y = (_Float16)v.y;
        h.z = (_Float16)v.z; h.w = (_Float16)v.w;
        *(half4*)&cT[row * ROWSTR + col] = h;
    }
    __syncthreads();

    const int wave = t >> 6;
    const int lane = t & 63;
    const int m16  = lane & 15;
    const int quad = lane >> 4;

    floatx4 acc[4][4] = {};   // [i: out-col tile][j: batch-row tile]

    const half8* wbase = (const half8*)wqp;   // units of 16B
#pragma unroll
    for (int ks = 0; ks < 8; ++ks) {
        half8 afr[4], bfr[4];
#pragma unroll
        for (int i = 0; i < 4; ++i)          // coalesced: consecutive lanes -> consecutive 16B
            afr[i] = wbase[((wave * 4 + i) * 8 + ks) * 64 + lane];
        const int kb = ks * 32 + quad * 8;
#pragma unroll
        for (int j = 0; j < 4; ++j)          // ds_read_b128, bank-balanced
            bfr[j] = *(const half8*)&cT[(j * 16 + m16) * ROWSTR + kb];
#pragma unroll
        for (int i = 0; i < 4; ++i)
#pragma unroll
            for (int j = 0; j < 4; ++j)
                acc[i][j] = __builtin_amdgcn_mfma_f32_16x16x32_f16(afr[i], bfr[j], acc[i][j], 0, 0, 0);
    }

    // ---- epilogue: lane owns 4 consecutive out cols -> float4 stores ----
#pragma unroll
    for (int i = 0; i < 4; ++i) {
        int col = wave * 64 + i * 16 + quad * 4;
        floatx4 bv = *(const floatx4*)(bq + col);
#pragma unroll
        for (int j = 0; j < 4; ++j) {
            size_t row = m0 + j * 16 + m16;
            floatx4 v = acc[i][j] + bv;
            *(floatx4*)(out + row * OUT_DIM + col) = v;
        }
    }
}

extern "C" void kernel_launch(void* const* d_in, const int* in_sizes, int n_in,
                              void* d_out, int out_size, void* d_ws, size_t ws_size,
                              hipStream_t stream) {
    const int*   cx       = (const int*)d_in[0];
    const float* w        = (const float*)d_in[1];
    const float* bias     = (const float*)d_in[2];
    const float* in_scale = (const float*)d_in[3];
    float* out = (float*)d_out;

    _Float16* wqp = (_Float16*)d_ws;                              // 128 KB, permuted
    float*    bq  = (float*)((char*)d_ws + OUT_DIM * IN_DIM * 2); // 1 KB

    const int rows = in_sizes[0] / IN_DIM;          // 65536
    const size_t gemm_elems = (size_t)rows * OUT_DIM;
    float* out_scalar = ((size_t)out_size > gemm_elems) ? (out + gemm_elems) : nullptr;

    quant_kernel<<<32, 256, 0, stream>>>(w, bias, in_scale, wqp, bq, out_scalar);
    gemm_kernel<<<rows / M_TILE, 256, 0, stream>>>(cx, wqp, bq, out);
}